// Round 5
// baseline (351.302 us; speedup 1.0000x reference)
//
#include <hip/hip_runtime.h>
#include <math.h>

typedef unsigned short ushort;
typedef unsigned int u32;
typedef short bf16x8 __attribute__((ext_vector_type(8)));
typedef ushort us8 __attribute__((ext_vector_type(8)));
typedef float f32x16 __attribute__((ext_vector_type(16)));
typedef float f32x4 __attribute__((ext_vector_type(4)));

// ---------------- workspace layout (float elements) ----------------
static const size_t OFF_POOLED = 0;         // 4096 f (2 inputs x 2048)
static const size_t OFF_WK     = 4096;      // 36864 f (2 x 16*128*9)
static const size_t OFF_WT     = 40960;     // Awt 294912 sh = 147456 f
static const size_t OFF_WF     = 188416;    // Wf 32768 sh = 16384 f
static const size_t OFF_AW1    = 204800;    // 9216 sh = 4608 f
static const size_t OFF_AW2    = 209408;    // 5120 sh = 2560 f
static const size_t OFF_T      = 262144;    // bufT 2x8M sh = 8388608 f ; R1 aliases
static const size_t OFF_AB     = 8650752;   // bufAB 2x8M sh = 8388608 f ; bufU aliases
static const size_t OFF_F      = 17039360;  // F 8388608 sh = 4194304 f
// total 21233664 f = 85 MB

static __device__ __forceinline__ ushort f2bf(float f) {
    unsigned int u = __builtin_bit_cast(unsigned int, f);
    u += 0x7FFF + ((u >> 16) & 1);
    return (ushort)(u >> 16);
}
static __device__ __forceinline__ float bf2f(ushort u) {
    return __builtin_bit_cast(float, ((unsigned int)u) << 16);
}

// ---------------- pooling (both inputs): pooled[bc] -------------------------
__global__ __launch_bounds__(256) void pool_both_kernel(const float* __restrict__ x1,
                                                        const float* __restrict__ x2,
                                                        float* __restrict__ pooled) {
    int bc = blockIdx.x;  // 4096
    const float* x = (bc >> 11) ? x2 : x1;
    const float4* p = (const float4*)(x + (size_t)(bc & 2047) * 4096);
    float s = 0.f;
    for (int i = threadIdx.x; i < 1024; i += 256) {
        float4 v = p[i];
        s += v.x + v.y + v.z + v.w;
    }
    #pragma unroll
    for (int off = 32; off; off >>= 1) s += __shfl_down(s, off);
    __shared__ float r4[4];
    if ((threadIdx.x & 63) == 0) r4[threadIdx.x >> 6] = s;
    __syncthreads();
    if (threadIdx.x == 0) pooled[bc] = (r4[0] + r4[1] + r4[2] + r4[3]) * (1.f / 4096.f);
}

// ------------- wk: gelu(pooled@w1^T)@w2^T -> softmax over 9 (grid 32) -------
__global__ __launch_bounds__(128) void wk_kernel(const float* __restrict__ pooled,
                                                 const float* __restrict__ w1,
                                                 const float* __restrict__ w2,
                                                 float* __restrict__ wk) {
    int b = blockIdx.x;
    __shared__ float sp[128];
    __shared__ float sh[16];
    int t = threadIdx.x;
    sp[t] = pooled[b * 128 + t];
    __syncthreads();
    if (t < 16) {
        float acc = 0.f;
        #pragma unroll 4
        for (int c = 0; c < 128; c++) acc += w1[t * 128 + c] * sp[c];
        sh[t] = 0.5f * acc * (1.f + erff(acc * 0.70710678118654752f));
    }
    __syncthreads();
    float lg[9];
    float m = -INFINITY;
    #pragma unroll
    for (int k = 0; k < 9; k++) {
        float acc = 0.f;
        const float* wr = w2 + (size_t)(t * 9 + k) * 16;
        #pragma unroll
        for (int r = 0; r < 16; r++) acc += wr[r] * sh[r];
        lg[k] = acc;
        m = fmaxf(m, acc);
    }
    float se = 0.f;
    #pragma unroll
    for (int k = 0; k < 9; k++) { lg[k] = expf(lg[k] - m); se += lg[k]; }
    float inv = 1.f / se;
    #pragma unroll
    for (int k = 0; k < 9; k++) wk[(size_t)(b * 128 + t) * 9 + k] = lg[k] * inv;
}

// -------- dsc1: f32 in, bf16 out, relu+pool (both inputs) -------------------
__global__ __launch_bounds__(256) void dsc1_kernel(const float* __restrict__ x1,
                                                   const float* __restrict__ x2,
                                                   const float* __restrict__ wk,
                                                   ushort* __restrict__ y,
                                                   float* __restrict__ pooled2) {
    int bc = blockIdx.x;  // 4096
    const float* xp = ((bc >> 11) ? x2 : x1) + (size_t)(bc & 2047) * 4096;
    ushort* yp = y + (size_t)bc * 4096;
    __shared__ float tile[66 * 66];
    __shared__ float r4[4];
    int t = threadIdx.x;
    for (int i = t; i < 66 * 66; i += 256) tile[i] = 0.f;
    __syncthreads();
    const float4* xp4 = (const float4*)xp;
    for (int i = t; i < 1024; i += 256) {
        float4 v = xp4[i];
        int h = i >> 4, w = (i & 15) * 4;
        float* d = &tile[(h + 1) * 66 + w + 1];
        d[0] = v.x; d[1] = v.y; d[2] = v.z; d[3] = v.w;
    }
    __syncthreads();
    float kk[9];
    #pragma unroll
    for (int k = 0; k < 9; k++) kk[k] = wk[(size_t)bc * 9 + k];
    float psum = 0.f;
    for (int i = t * 2; i < 4096; i += 512) {
        int h = i >> 6, w = i & 63;
        const float* c = &tile[h * 66 + w];
        float v0 = kk[0]*c[0] + kk[1]*c[1] + kk[2]*c[2]
                 + kk[3]*c[66] + kk[4]*c[67] + kk[5]*c[68]
                 + kk[6]*c[132] + kk[7]*c[133] + kk[8]*c[134] + c[67];
        float v1 = kk[0]*c[1] + kk[1]*c[2] + kk[2]*c[3]
                 + kk[3]*c[67] + kk[4]*c[68] + kk[5]*c[69]
                 + kk[6]*c[133] + kk[7]*c[134] + kk[8]*c[135] + c[68];
        v0 = fmaxf(v0, 0.f); v1 = fmaxf(v1, 0.f);
        psum += v0 + v1;
        ushort2 pk = {f2bf(v0), f2bf(v1)};
        *(ushort2*)&yp[i] = pk;
    }
    #pragma unroll
    for (int off = 32; off; off >>= 1) psum += __shfl_down(psum, off);
    if ((t & 63) == 0) r4[t >> 6] = psum;
    __syncthreads();
    if (t == 0) pooled2[bc] = (r4[0] + r4[1] + r4[2] + r4[3]) * (1.f / 4096.f);
}

// -------- dsc2: bf16 in, bf16 out (both inputs) -----------------------------
__global__ __launch_bounds__(256) void dsc2_kernel(const ushort* __restrict__ x,
                                                   const float* __restrict__ wk,
                                                   ushort* __restrict__ y) {
    int bc = blockIdx.x;  // 4096
    const ushort* xp = x + (size_t)bc * 4096;
    ushort* yp = y + (size_t)bc * 4096;
    __shared__ float tile[66 * 66];
    int t = threadIdx.x;
    for (int i = t; i < 66 * 66; i += 256) tile[i] = 0.f;
    __syncthreads();
    for (int i = t; i < 512; i += 256) {
        int4 raw = *(const int4*)&xp[i * 8];
        const ushort* u = (const ushort*)&raw;
        int h = i >> 3, w = (i & 7) * 8;
        float* d = &tile[(h + 1) * 66 + w + 1];
        #pragma unroll
        for (int j = 0; j < 8; j++) d[j] = bf2f(u[j]);
    }
    __syncthreads();
    float kk[9];
    #pragma unroll
    for (int k = 0; k < 9; k++) kk[k] = wk[(size_t)bc * 9 + k];
    for (int i = t * 2; i < 4096; i += 512) {
        int h = i >> 6, w = i & 63;
        const float* c = &tile[h * 66 + w];
        float v0 = kk[0]*c[0] + kk[1]*c[1] + kk[2]*c[2]
                 + kk[3]*c[66] + kk[4]*c[67] + kk[5]*c[68]
                 + kk[6]*c[132] + kk[7]*c[133] + kk[8]*c[134] + c[67];
        float v1 = kk[0]*c[1] + kk[1]*c[2] + kk[2]*c[3]
                 + kk[3]*c[67] + kk[4]*c[68] + kk[5]*c[69]
                 + kk[6]*c[133] + kk[7]*c[134] + kk[8]*c[135] + c[68];
        ushort2 pk = {f2bf(v0), f2bf(v1)};
        *(ushort2*)&yp[i] = pk;
    }
}

// ---- align weight prep: Wf [step(16)][mt(4)][lane(64)][8] ------------------
__global__ __launch_bounds__(256) void awprep_kernel(const float* __restrict__ W,
                                                     ushort* __restrict__ Wf) {
    int t = threadIdx.x;
    #pragma unroll 1
    for (int i = 0; i < 16; i++) {
        int tk = t + (i << 8);
        int step = tk >> 8, mt = (tk >> 6) & 3, lane = tk & 63;
        int o = mt * 32 + (lane & 31);
        int cb = step * 16 + (lane >> 5) * 8;
        #pragma unroll
        for (int j = 0; j < 8; j++) Wf[(size_t)tk * 8 + j] = f2bf(W[o * 256 + cb + j]);
    }
}

// ---- align: F[b][px][128c] = W @ concat(A,B), bf16 MFMA --------------------
__global__ __launch_bounds__(256, 2) void align_mfma_kernel(const ushort* __restrict__ A,
                                                            const ushort* __restrict__ Bv,
                                                            const ushort* __restrict__ Wf,
                                                            ushort* __restrict__ F) {
    __shared__ ushort Xs[2 * 128 * 8];
    const int b = blockIdx.y;
    const int px0 = blockIdx.x << 7;
    const int tid = threadIdx.x;
    const int wave = tid >> 6, lane = tid & 63;
    const int l31 = lane & 31, half = lane >> 5;

    f32x16 acc[4];
    #pragma unroll
    for (int mt = 0; mt < 4; mt++)
        #pragma unroll
        for (int r = 0; r < 16; r++) acc[mt][r] = 0.f;

    const int cg0 = tid >> 7, pxs0 = tid & 127;
    const int bfofs = (wave * 32 + l31) * 8 + half * 1024;

    for (int step = 0; step < 16; step++) {
        const ushort* src =
            (step < 8 ? A : Bv) + (((size_t)(b * 128 + (step & 7) * 16)) << 12) + px0;
        if (step) __syncthreads();
        #pragma unroll
        for (int q = 0; q < 2; q++) {
            int cg = cg0 + q * 2, px = pxs0;
            ushort v0 = src[((size_t)(cg * 4 + 0) << 12) + px];
            ushort v1 = src[((size_t)(cg * 4 + 1) << 12) + px];
            ushort v2 = src[((size_t)(cg * 4 + 2) << 12) + px];
            ushort v3 = src[((size_t)(cg * 4 + 3) << 12) + px];
            ushort4 pk = {v0, v1, v2, v3};
            *(ushort4*)&Xs[(cg >> 1) * 1024 + px * 8 + (cg & 1) * 4] = pk;
        }
        __syncthreads();
        bf16x8 bfrag = *(const bf16x8*)&Xs[bfofs];
        const bf16x8* wf = (const bf16x8*)(Wf + ((size_t)step * 4 * 64 + lane) * 8);
        #pragma unroll
        for (int mt = 0; mt < 4; mt++)
            acc[mt] = __builtin_amdgcn_mfma_f32_32x32x16_bf16(wf[mt * 64], bfrag, acc[mt], 0, 0, 0);
    }
    // epilogue: F[b][px][c]; o = mt*32 + half*4 + 8*g + i
    ushort* fp = F + ((size_t)(b * 4096 + px0 + wave * 32 + l31)) * 128;
    #pragma unroll
    for (int mt = 0; mt < 4; mt++) {
        #pragma unroll
        for (int g = 0; g < 4; g++) {
            ushort4 pk = {f2bf(acc[mt][g * 4 + 0]), f2bf(acc[mt][g * 4 + 1]),
                          f2bf(acc[mt][g * 4 + 2]), f2bf(acc[mt][g * 4 + 3])};
            *(ushort4*)(fp + mt * 32 + half * 4 + 8 * g) = pk;
        }
    }
}

// ---- combined up weight, A-frag order: Awt[s=tap*8+c16][mh(2)][mt(4)][lane][8]
// SEMANTIC op reorder for direct epilogue stores:
//   A-row arow=lane&31 in tile (mh,mt) represents output channel
//     o_sem = 32*(mt&1) + (arow&3) + 4*((arow>>3)&3) + 16*((arow>>2)&1)
//   at pixel-shuffle phase ph = 2*mh + (mt>>1)  (ry=mh, rx=mt>>1).
//   With D-row d=(r&3)+8*(r>>2)+4*half this makes lane channels = 32*(mt&1)+16*half + r
//   (16 CONSECUTIVE channels -> two 16B global stores per (mt,nt)).
__global__ __launch_bounds__(256) void wcomb_kernel(const float* __restrict__ w1,
                                                    const float* __restrict__ w2,
                                                    ushort* __restrict__ Awt) {
    int idx = blockIdx.x * 256 + threadIdx.x;  // < 294912
    int j = idx & 7;
    int lane = (idx >> 3) & 63;
    int mt = (idx >> 9) & 3;
    int mh = (idx >> 11) & 1;
    int s = idx >> 12;             // 0..71
    int tap = s >> 3, c16 = s & 7;
    int arow = lane & 31;
    int o_sem = (mt & 1) * 32 + (arow & 3) + 4 * ((arow >> 3) & 3) + 16 * ((arow >> 2) & 1);
    int ph = 2 * mh + (mt >> 1);
    int cin = c16 * 16 + (lane >> 5) * 8 + j;
    float acc = 0.f;
    #pragma unroll 4
    for (int c = 0; c < 128; c++)
        acc += w2[o_sem * 128 + c] * w1[((size_t)(c * 4 + ph) * 128 + cin) * 9 + tap];
    Awt[idx] = f2bf(acc);
}

// ---- re1 weight prep: Aw1[s(18)][lane(64)][8]  (16x16x32 A-frag order) -----
__global__ __launch_bounds__(256) void aw1prep_kernel(const float* __restrict__ w1,  // [8,64,3,3]
                                                      ushort* __restrict__ Aw1) {
    int idx = blockIdx.x * 256 + threadIdx.x;  // < 9216
    if (idx >= 9216) return;
    int j = idx & 7, lane = (idx >> 3) & 63, s = idx >> 9;
    int m = lane & 15, kq = lane >> 4;
    int tap = s >> 1, ch = s & 1;
    int cin = ch * 32 + kq * 8 + j;
    float v = (m < 8) ? w1[((size_t)(m * 64 + cin)) * 9 + tap] : 0.f;
    Aw1[idx] = f2bf(v);
}

// ---- re2 weight prep: Aw2[s(5)][mt(2)][lane(64)][8] (32x32x16 A-frag) ------
__global__ __launch_bounds__(256) void aw2prep_kernel(const float* __restrict__ w2,  // [64,8,3,3]
                                                      ushort* __restrict__ Aw2) {
    int idx = blockIdx.x * 256 + threadIdx.x;  // < 5120
    if (idx >= 5120) return;
    int j = idx & 7, lane = (idx >> 3) & 63, mt = (idx >> 9) & 1, s = idx >> 10;
    int m = mt * 32 + (lane & 31), half = lane >> 5;
    int k = s * 16 + half * 8 + j;
    int tap = k >> 3, c = k & 7;
    float v = (tap < 9) ? w2[((size_t)(m * 8 + c)) * 9 + tap] : 0.f;
    Aw2[idx] = f2bf(v);
}

// ------ up-conv: implicit GEMM 32x32x16 bf16, F[b,px,c] -> U[b,Y,X,64] ------
// T3/T4: A staged once per block via global_load_lds into a 4-slot LDS ring
// (8KB/step, halves L2 traffic vs per-wave loads). Counted vmcnt(2) in the main
// loop (never drained), stage distance 3, read distance 1, barrier per step,
// sched_barrier(0) pins Abuf ds_reads behind the wait (rule #18), setprio (T5).
// B: distance-1 reads from swizzled halo. Direct-store epilogue.
__global__ __launch_bounds__(256, 2) void up_mfma_kernel(const ushort* __restrict__ F,
                                                         const ushort* __restrict__ Awt,
                                                         ushort* __restrict__ U) {
    __shared__ ushort Xs[180 * 128];    // 46080 B halo
    __shared__ ushort Abuf[4 * 4096];   // 32768 B A ring (4 slots x 8KB)
    const int b = blockIdx.y;
    const int tr = blockIdx.x >> 3, tc = blockIdx.x & 7;
    const int tid = threadIdx.x;
    const int wave = tid >> 6, lane = tid & 63;
    const int l31 = lane & 31, half = lane >> 5;
    const int mh = wave >> 1, nh = wave & 1;

    // async A-stage: wave w DMAs its 2KB quarter of step ss into ring slot ss&3
    #define STAGE_A(ss) do {                                                        \
        int sb_ = (ss) & 3;                                                         \
        const ushort* g0_ = Awt + (size_t)(ss) * 4096 + wave * 1024 + lane * 8;     \
        __builtin_amdgcn_global_load_lds(                                           \
            (const __attribute__((address_space(1))) u32*)g0_,                      \
            (__attribute__((address_space(3))) u32*)&Abuf[sb_ * 4096 + wave * 1024],\
            16, 0, 0);                                                              \
        __builtin_amdgcn_global_load_lds(                                           \
            (const __attribute__((address_space(1))) u32*)(g0_ + 512),              \
            (__attribute__((address_space(3))) u32*)&Abuf[sb_ * 4096 + wave * 1024 + 512], \
            16, 0, 0);                                                              \
    } while (0)

    // issue first 3 A-steps; they land under the halo staging + syncthreads drain
    STAGE_A(0); STAGE_A(1); STAGE_A(2);

    // stage whole 18x10 halo x 128c; unit q stored at slot q ^ (px&7)
    for (int idx = tid; idx < 2880; idx += 256) {
        int px = idx >> 4, q = idx & 15;
        int r = px / 10, c = px - r * 10;
        int gh = tr * 16 - 1 + r, gw = tc * 8 - 1 + c;
        int4 v = {0, 0, 0, 0};
        if ((unsigned)gh < 64u && (unsigned)gw < 64u)
            v = *(const int4*)(F + ((size_t)(b * 4096 + gh * 64 + gw)) * 128 + q * 8);
        *(int4*)&Xs[px * 128 + ((q ^ (px & 7)) << 3)] = v;
    }
    __syncthreads();  // drains vmcnt+lgkmcnt: halo and A-steps 0..2 all visible

    f32x16 acc[4][2];
    #pragma unroll
    for (int mt = 0; mt < 4; mt++)
        #pragma unroll
        for (int nt = 0; nt < 2; nt++)
            #pragma unroll
            for (int r = 0; r < 16; r++) acc[mt][nt][r] = 0.f;

    int xpos[2];
    #pragma unroll
    for (int nt = 0; nt < 2; nt++) {
        int pxl = nh * 64 + nt * 32 + l31;
        xpos[nt] = (pxl >> 3) * 10 + (pxl & 7);
    }

    #define LDA(ss, mt) (*(const bf16x8*)&Abuf[((ss) & 3) * 4096 + (mh * 4 + (mt)) * 512 + lane * 8])
    #define LDB(ss, nt) ({                                                   \
        int tap_ = (ss) >> 3, c16_ = (ss) & 7;                               \
        int ky_ = (tap_ * 11) >> 5;  /* tap/3 for 0..8 */                    \
        int kx_ = tap_ - ky_ * 3;                                            \
        int p_ = xpos[nt] + ky_ * 10 + kx_;                                  \
        int qq_ = c16_ * 2 + half;                                           \
        *(const bf16x8*)&Xs[p_ * 128 + ((qq_ ^ (p_ & 7)) << 3)];             \
    })

    bf16x8 A0[4], A1[4], B0[2], B1[2];
    #pragma unroll
    for (int mt = 0; mt < 4; mt++) A0[mt] = LDA(0, mt);
    B0[0] = LDB(0, 0); B0[1] = LDB(0, 1);

    #define MFMA8(ASET, BSET)                                                        \
        __builtin_amdgcn_s_setprio(1);                                               \
        _Pragma("unroll")                                                            \
        for (int mt = 0; mt < 4; mt++) {                                             \
            acc[mt][0] = __builtin_amdgcn_mfma_f32_32x32x16_bf16(ASET[mt], BSET[0], acc[mt][0], 0, 0, 0); \
            acc[mt][1] = __builtin_amdgcn_mfma_f32_32x32x16_bf16(ASET[mt], BSET[1], acc[mt][1], 0, 0, 0); \
        }                                                                            \
        __builtin_amdgcn_s_setprio(0);

    #define HDR(VMC)                                                                 \
        asm volatile("s_waitcnt vmcnt(" #VMC ")" ::: "memory");                      \
        __builtin_amdgcn_s_barrier();                                                \
        __builtin_amdgcn_sched_barrier(0);

    #define RD(DST_A, DST_B, ss)                                                     \
        _Pragma("unroll")                                                            \
        for (int mt = 0; mt < 4; mt++) DST_A[mt] = LDA(ss, mt);                      \
        DST_B[0] = LDB(ss, 0); DST_B[1] = LDB(ss, 1);

    #pragma unroll 1
    for (int s = 0; s < 68; s += 2) {
        // even body: consume s (A0/B0), read s+1, stage s+3
        HDR(2) STAGE_A(s + 3); RD(A1, B1, s + 1) MFMA8(A0, B0)
        // odd body: consume s+1 (A1/B1), read s+2, stage s+4
        HDR(2) STAGE_A(s + 4); RD(A0, B0, s + 2) MFMA8(A1, B1)
    }
    // tails: s = 68..71
    HDR(2) STAGE_A(71); RD(A1, B1, 69) MFMA8(A0, B0)   // s=68
    HDR(2)              RD(A0, B0, 70) MFMA8(A1, B1)   // s=69 (70,71 in flight)
    HDR(0)              RD(A1, B1, 71) MFMA8(A0, B0)   // s=70 (drain: 71 landed)
    MFMA8(A1, B1)                                      // s=71
    #undef HDR
    #undef RD
    #undef MFMA8
    #undef LDA
    #undef LDB
    #undef STAGE_A

    // direct epilogue: per (mt,nt) two 16B stores of 8 consecutive channels
    // Y = 2*(tr*16+h)+mh, X = 2*(tc*8+w)+(mt>>1), ch = 32*(mt&1)+16*half + r
    #pragma unroll
    for (int nt = 0; nt < 2; nt++) {
        int pxl = nh * 64 + nt * 32 + l31;
        int Y = 2 * (tr * 16 + (pxl >> 3)) + mh;
        int X = 2 * (tc * 8 + (pxl & 7));
        #pragma unroll
        for (int mt = 0; mt < 4; mt++) {
            ushort* up = U + ((size_t)((b * 128 + Y) * 128 + X + (mt >> 1))) * 64
                       + (mt & 1) * 32 + half * 16;
            us8 p0, p1;
            #pragma unroll
            for (int i = 0; i < 8; i++) {
                p0[i] = f2bf(acc[mt][nt][i]);
                p1[i] = f2bf(acc[mt][nt][8 + i]);
            }
            *(us8*)up = p0;
            *(us8*)(up + 8) = p1;
        }
    }
}

// ------ re1: conv3x3(U,re_w1)+relu via 16x16x32 MFMA -> R1[b,Y,X,8] ---------
__global__ __launch_bounds__(256, 2) void re1_kernel(const ushort* __restrict__ U,
                                                     const ushort* __restrict__ Aw1,
                                                     ushort* __restrict__ R1) {
    __shared__ ushort Xs[324 * 72];  // 46656 B
    __shared__ ushort As[18 * 64 * 8];
    const int b = blockIdx.y;
    const int ty = blockIdx.x >> 3, tx = blockIdx.x & 7;
    const int tid = threadIdx.x;
    const int wave = tid >> 6, lane = tid & 63;
    const int m16 = lane & 15, kq = lane >> 4;

    for (int idx = tid; idx < 1152; idx += 256)
        *(int4*)&As[idx * 8] = *(const int4*)(Aw1 + (size_t)idx * 8);
    for (int idx = tid; idx < 2592; idx += 256) {
        int px = idx >> 3, q = idx & 7;
        int r = px / 18, c = px - r * 18;
        int gY = ty * 16 - 1 + r, gX = tx * 16 - 1 + c;
        int4 v = {0, 0, 0, 0};
        if ((unsigned)gY < 128u && (unsigned)gX < 128u)
            v = *(const int4*)(U + ((size_t)((b * 128 + gY) * 128 + gX)) * 64 + q * 8);
        *(int4*)&Xs[px * 72 + q * 8] = v;
    }
    __syncthreads();

    f32x4 acc[4];
    #pragma unroll
    for (int nt = 0; nt < 4; nt++)
        #pragma unroll
        for (int r = 0; r < 4; r++) acc[nt][r] = 0.f;

    #pragma unroll 1
    for (int s = 0; s < 18; s++) {
        bf16x8 a = *(const bf16x8*)&As[(s * 64 + lane) * 8];
        int tap = s >> 1, ch = s & 1;
        int ky = tap / 3, kx = tap - ky * 3;
        int xo = (ky * 18 + kx) * 72 + ch * 32 + kq * 8;
        #pragma unroll
        for (int nt = 0; nt < 4; nt++) {
            int row = wave * 4 + nt;
            bf16x8 bv = *(const bf16x8*)&Xs[(row * 18 + m16) * 72 + xo];
            acc[nt] = __builtin_amdgcn_mfma_f32_16x16x32_bf16(a, bv, acc[nt], 0, 0, 0);
        }
    }
    if (kq < 2) {
        #pragma unroll
        for (int nt = 0; nt < 4; nt++) {
            int gY = ty * 16 + wave * 4 + nt, gX = tx * 16 + m16;
            ushort4 pk = {f2bf(fmaxf(acc[nt][0], 0.f)), f2bf(fmaxf(acc[nt][1], 0.f)),
                          f2bf(fmaxf(acc[nt][2], 0.f)), f2bf(fmaxf(acc[nt][3], 0.f))};
            *(ushort4*)(R1 + ((size_t)((b * 128 + gY) * 128 + gX)) * 8 + kq * 4) = pk;
        }
    }
}

// ------ re2: conv3x3(R1,re_w2) + up  via 32x32x16 MFMA -> out f32 planar ----
__global__ __launch_bounds__(256, 2) void re2_kernel(const ushort* __restrict__ R1,
                                                     const ushort* __restrict__ U,
                                                     const ushort* __restrict__ Aw2,
                                                     float* __restrict__ out) {
    __shared__ ushort Xs[324 * 8];   // 5184 B
    __shared__ ushort As[5 * 2 * 64 * 8];
    __shared__ ushort Us[256 * 68];  // 34816 B
    const int b = blockIdx.y;
    const int ty = blockIdx.x >> 3, tx = blockIdx.x & 7;
    const int tid = threadIdx.x;
    const int wave = tid >> 6, lane = tid & 63;
    const int l31 = lane & 31, half = lane >> 5;

    for (int idx = tid; idx < 640; idx += 256)
        *(int4*)&As[idx * 8] = *(const int4*)(Aw2 + (size_t)idx * 8);
    for (int idx = tid; idx < 324; idx += 256) {
        int r = idx / 18, c = idx - r * 18;
        int gY = ty * 16 - 1 + r, gX = tx * 16 - 1 + c;
        int4 v = {0, 0, 0, 0};
        if ((unsigned)gY < 128u && (unsigned)gX < 128u)
            v = *(const int4*)(R1 + ((size_t)((b * 128 + gY) * 128 + gX)) * 8);
        *(int4*)&Xs[idx * 8] = v;
    }
    for (int idx = tid; idx < 2048; idx += 256) {
        int px = idx >> 3, q = idx & 7;
        int gY = ty * 16 + (px >> 4), gX = tx * 16 + (px & 15);
        const ushort* s = U + ((size_t)((b * 128 + gY) * 128 + gX)) * 64 + q * 8;
        ushort4 v0 = *(const ushort4*)s;
        ushort4 v1 = *(const ushort4*)(s + 4);
        *(ushort4*)&Us[px * 68 + q * 8] = v0;
        *(ushort4*)&Us[px * 68 + q * 8 + 4] = v1;
    }
    __syncthreads();

    f32x16 acc[2][2];
    #pragma unroll
    for (int mt = 0; mt < 2; mt++)
        #pragma unroll
        for (int nt = 0; nt < 2; nt++)
            #pragma unroll
            for (int r = 0; r < 16; r++) acc[mt][nt][r] = 0.f;

    #pragma unroll
    for (int s = 0; s < 5; s++) {
        bf16x8 a0 = *(const bf16x8*)&As[((s * 2 + 0) * 64 + lane) * 8];
        bf16x8 a1 = *(const bf16x8*)&As[((s * 2 + 1) * 64 + lane) * 8];
        int t = 2 * s + half;
        if (t > 8) t = 8;  // A is zero there
        int ky = t / 3, kx = t - ky * 3;
        #pragma unroll
        for (int nt = 0; nt < 2; nt++) {
            int pxl = wave * 64 + nt * 32 + l31;
            int row = pxl >> 4, col = pxl & 15;
            bf16x8 bv = *(const bf16x8*)&Xs[((row + ky) * 18 + col + kx) * 8];
            acc[0][nt] = __builtin_amdgcn_mfma_f32_32x32x16_bf16(a0, bv, acc[0][nt], 0, 0, 0);
            acc[1][nt] = __builtin_amdgcn_mfma_f32_32x32x16_bf16(a1, bv, acc[1][nt], 0, 0, 0);
        }
    }
    #pragma unroll
    for (int mt = 0; mt < 2; mt++) {
        #pragma unroll
        for (int nt = 0; nt < 2; nt++) {
            int pxl = wave * 64 + nt * 32 + l31;
            int gY = ty * 16 + (pxl >> 4), gX = tx * 16 + (pxl & 15);
            #pragma unroll
            for (int r = 0; r < 16; r++) {
                int o = mt * 32 + (r & 3) + 8 * (r >> 2) + 4 * half;
                float v = acc[mt][nt][r] + bf2f(Us[pxl * 68 + o]);
                out[((size_t)(b * 64 + o) * 128 + gY) * 128 + gX] = v;
            }
        }
    }
}

extern "C" void kernel_launch(void* const* d_in, const int* in_sizes, int n_in,
                              void* d_out, int out_size, void* d_ws, size_t ws_size,
                              hipStream_t stream) {
    const float* x1      = (const float*)d_in[0];
    const float* x2      = (const float*)d_in[1];
    const float* d1_w1   = (const float*)d_in[2];
    const float* d1_w2   = (const float*)d_in[3];
    const float* d2_w1   = (const float*)d_in[4];
    const float* d2_w2   = (const float*)d_in[5];
    const float* align_w = (const float*)d_in[6];
    const float* up_w1   = (const float*)d_in[7];
    const float* up_w2   = (const float*)d_in[8];
    const float* re_w1   = (const float*)d_in[9];
    const float* re_w2   = (const float*)d_in[10];
    float* out = (float*)d_out;
    float* ws  = (float*)d_ws;

    float*  pooled = ws + OFF_POOLED;
    float*  wkb    = ws + OFF_WK;
    ushort* Awt    = (ushort*)(ws + OFF_WT);
    ushort* Wf     = (ushort*)(ws + OFF_WF);
    ushort* Aw1    = (ushort*)(ws + OFF_AW1);
    ushort* Aw2    = (ushort*)(ws + OFF_AW2);
    ushort* bufT   = (ushort*)(ws + OFF_T);
    ushort* R1     = (ushort*)(ws + OFF_T);   // alias (bufT dead by re1)
    ushort* bufAB  = (ushort*)(ws + OFF_AB);
    ushort* bufU   = (ushort*)(ws + OFF_AB);  // alias (bufAB dead after align)
    ushort* F      = (ushort*)(ws + OFF_F);

    wcomb_kernel<<<1152, 256, 0, stream>>>(up_w1, up_w2, Awt);
    awprep_kernel<<<1, 256, 0, stream>>>(align_w, Wf);
    aw1prep_kernel<<<36, 256, 0, stream>>>(re_w1, Aw1);
    aw2prep_kernel<<<20, 256, 0, stream>>>(re_w2, Aw2);

    pool_both_kernel<<<4096, 256, 0, stream>>>(x1, x2, pooled);
    wk_kernel<<<32, 128, 0, stream>>>(pooled, d1_w1, d1_w2, wkb);
    dsc1_kernel<<<4096, 256, 0, stream>>>(x1, x2, wkb, bufT, pooled);
    wk_kernel<<<32, 128, 0, stream>>>(pooled, d2_w1, d2_w2, wkb);
    dsc2_kernel<<<4096, 256, 0, stream>>>(bufT, wkb, bufAB);

    align_mfma_kernel<<<dim3(32, 16), 256, 0, stream>>>(bufAB, bufAB + 8388608, Wf, F);
    up_mfma_kernel<<<dim3(32, 16), 256, 0, stream>>>(F, Awt, bufU);
    re1_kernel<<<dim3(64, 16), 256, 0, stream>>>(bufU, Aw1, R1);
    re2_kernel<<<dim3(64, 16), 256, 0, stream>>>(R1, bufU, Aw2, out);
}

// Round 6
// 336.266 us; speedup vs baseline: 1.0447x; 1.0447x over previous
//
#include <hip/hip_runtime.h>
#include <math.h>

typedef unsigned short ushort;
typedef short bf16x8 __attribute__((ext_vector_type(8)));
typedef ushort us8 __attribute__((ext_vector_type(8)));
typedef float f32x16 __attribute__((ext_vector_type(16)));
typedef float f32x4 __attribute__((ext_vector_type(4)));

// ---------------- workspace layout (float elements) ----------------
static const size_t OFF_POOLED = 0;         // 4096 f (2 inputs x 2048)
static const size_t OFF_WK     = 4096;      // 36864 f (2 x 16*128*9)
static const size_t OFF_WT     = 40960;     // Awt 294912 sh = 147456 f
static const size_t OFF_WF     = 188416;    // Wf 32768 sh = 16384 f
static const size_t OFF_AW1    = 204800;    // 9216 sh = 4608 f
static const size_t OFF_AW2    = 209408;    // 5120 sh = 2560 f
static const size_t OFF_T      = 262144;    // bufT 2x8M sh = 8388608 f ; R1 aliases
static const size_t OFF_AB     = 8650752;   // bufAB 2x8M sh = 8388608 f ; bufU aliases
static const size_t OFF_F      = 17039360;  // F 8388608 sh = 4194304 f
// total 21233664 f = 85 MB

static __device__ __forceinline__ ushort f2bf(float f) {
    unsigned int u = __builtin_bit_cast(unsigned int, f);
    u += 0x7FFF + ((u >> 16) & 1);
    return (ushort)(u >> 16);
}
static __device__ __forceinline__ float bf2f(ushort u) {
    return __builtin_bit_cast(float, ((unsigned int)u) << 16);
}

// ---------------- pooling (both inputs): pooled[bc] -------------------------
__global__ __launch_bounds__(256) void pool_both_kernel(const float* __restrict__ x1,
                                                        const float* __restrict__ x2,
                                                        float* __restrict__ pooled) {
    int bc = blockIdx.x;  // 4096
    const float* x = (bc >> 11) ? x2 : x1;
    const float4* p = (const float4*)(x + (size_t)(bc & 2047) * 4096);
    float s = 0.f;
    for (int i = threadIdx.x; i < 1024; i += 256) {
        float4 v = p[i];
        s += v.x + v.y + v.z + v.w;
    }
    #pragma unroll
    for (int off = 32; off; off >>= 1) s += __shfl_down(s, off);
    __shared__ float r4[4];
    if ((threadIdx.x & 63) == 0) r4[threadIdx.x >> 6] = s;
    __syncthreads();
    if (threadIdx.x == 0) pooled[bc] = (r4[0] + r4[1] + r4[2] + r4[3]) * (1.f / 4096.f);
}

// ------------- wk: gelu(pooled@w1^T)@w2^T -> softmax over 9 (grid 32) -------
__global__ __launch_bounds__(128) void wk_kernel(const float* __restrict__ pooled,
                                                 const float* __restrict__ w1,
                                                 const float* __restrict__ w2,
                                                 float* __restrict__ wk) {
    int b = blockIdx.x;
    __shared__ float sp[128];
    __shared__ float sh[16];
    int t = threadIdx.x;
    sp[t] = pooled[b * 128 + t];
    __syncthreads();
    if (t < 16) {
        float acc = 0.f;
        #pragma unroll 4
        for (int c = 0; c < 128; c++) acc += w1[t * 128 + c] * sp[c];
        sh[t] = 0.5f * acc * (1.f + erff(acc * 0.70710678118654752f));
    }
    __syncthreads();
    float lg[9];
    float m = -INFINITY;
    #pragma unroll
    for (int k = 0; k < 9; k++) {
        float acc = 0.f;
        const float* wr = w2 + (size_t)(t * 9 + k) * 16;
        #pragma unroll
        for (int r = 0; r < 16; r++) acc += wr[r] * sh[r];
        lg[k] = acc;
        m = fmaxf(m, acc);
    }
    float se = 0.f;
    #pragma unroll
    for (int k = 0; k < 9; k++) { lg[k] = expf(lg[k] - m); se += lg[k]; }
    float inv = 1.f / se;
    #pragma unroll
    for (int k = 0; k < 9; k++) wk[(size_t)(b * 128 + t) * 9 + k] = lg[k] * inv;
}

// -------- dsc1: f32 in, bf16 out, relu+pool (both inputs) -------------------
__global__ __launch_bounds__(256) void dsc1_kernel(const float* __restrict__ x1,
                                                   const float* __restrict__ x2,
                                                   const float* __restrict__ wk,
                                                   ushort* __restrict__ y,
                                                   float* __restrict__ pooled2) {
    int bc = blockIdx.x;  // 4096
    const float* xp = ((bc >> 11) ? x2 : x1) + (size_t)(bc & 2047) * 4096;
    ushort* yp = y + (size_t)bc * 4096;
    __shared__ float tile[66 * 66];
    __shared__ float r4[4];
    int t = threadIdx.x;
    for (int i = t; i < 66 * 66; i += 256) tile[i] = 0.f;
    __syncthreads();
    const float4* xp4 = (const float4*)xp;
    for (int i = t; i < 1024; i += 256) {
        float4 v = xp4[i];
        int h = i >> 4, w = (i & 15) * 4;
        float* d = &tile[(h + 1) * 66 + w + 1];
        d[0] = v.x; d[1] = v.y; d[2] = v.z; d[3] = v.w;
    }
    __syncthreads();
    float kk[9];
    #pragma unroll
    for (int k = 0; k < 9; k++) kk[k] = wk[(size_t)bc * 9 + k];
    float psum = 0.f;
    for (int i = t * 2; i < 4096; i += 512) {
        int h = i >> 6, w = i & 63;
        const float* c = &tile[h * 66 + w];
        float v0 = kk[0]*c[0] + kk[1]*c[1] + kk[2]*c[2]
                 + kk[3]*c[66] + kk[4]*c[67] + kk[5]*c[68]
                 + kk[6]*c[132] + kk[7]*c[133] + kk[8]*c[134] + c[67];
        float v1 = kk[0]*c[1] + kk[1]*c[2] + kk[2]*c[3]
                 + kk[3]*c[67] + kk[4]*c[68] + kk[5]*c[69]
                 + kk[6]*c[133] + kk[7]*c[134] + kk[8]*c[135] + c[68];
        v0 = fmaxf(v0, 0.f); v1 = fmaxf(v1, 0.f);
        psum += v0 + v1;
        ushort2 pk = {f2bf(v0), f2bf(v1)};
        *(ushort2*)&yp[i] = pk;
    }
    #pragma unroll
    for (int off = 32; off; off >>= 1) psum += __shfl_down(psum, off);
    if ((t & 63) == 0) r4[t >> 6] = psum;
    __syncthreads();
    if (t == 0) pooled2[bc] = (r4[0] + r4[1] + r4[2] + r4[3]) * (1.f / 4096.f);
}

// -------- dsc2: bf16 in, bf16 out (both inputs) -----------------------------
__global__ __launch_bounds__(256) void dsc2_kernel(const ushort* __restrict__ x,
                                                   const float* __restrict__ wk,
                                                   ushort* __restrict__ y) {
    int bc = blockIdx.x;  // 4096
    const ushort* xp = x + (size_t)bc * 4096;
    ushort* yp = y + (size_t)bc * 4096;
    __shared__ float tile[66 * 66];
    int t = threadIdx.x;
    for (int i = t; i < 66 * 66; i += 256) tile[i] = 0.f;
    __syncthreads();
    for (int i = t; i < 512; i += 256) {
        int4 raw = *(const int4*)&xp[i * 8];
        const ushort* u = (const ushort*)&raw;
        int h = i >> 3, w = (i & 7) * 8;
        float* d = &tile[(h + 1) * 66 + w + 1];
        #pragma unroll
        for (int j = 0; j < 8; j++) d[j] = bf2f(u[j]);
    }
    __syncthreads();
    float kk[9];
    #pragma unroll
    for (int k = 0; k < 9; k++) kk[k] = wk[(size_t)bc * 9 + k];
    for (int i = t * 2; i < 4096; i += 512) {
        int h = i >> 6, w = i & 63;
        const float* c = &tile[h * 66 + w];
        float v0 = kk[0]*c[0] + kk[1]*c[1] + kk[2]*c[2]
                 + kk[3]*c[66] + kk[4]*c[67] + kk[5]*c[68]
                 + kk[6]*c[132] + kk[7]*c[133] + kk[8]*c[134] + c[67];
        float v1 = kk[0]*c[1] + kk[1]*c[2] + kk[2]*c[3]
                 + kk[3]*c[67] + kk[4]*c[68] + kk[5]*c[69]
                 + kk[6]*c[133] + kk[7]*c[134] + kk[8]*c[135] + c[68];
        ushort2 pk = {f2bf(v0), f2bf(v1)};
        *(ushort2*)&yp[i] = pk;
    }
}

// ---- align weight prep: Wf [step(16)][mt(4)][lane(64)][8] ------------------
__global__ __launch_bounds__(256) void awprep_kernel(const float* __restrict__ W,
                                                     ushort* __restrict__ Wf) {
    int t = threadIdx.x;
    #pragma unroll 1
    for (int i = 0; i < 16; i++) {
        int tk = t + (i << 8);
        int step = tk >> 8, mt = (tk >> 6) & 3, lane = tk & 63;
        int o = mt * 32 + (lane & 31);
        int cb = step * 16 + (lane >> 5) * 8;
        #pragma unroll
        for (int j = 0; j < 8; j++) Wf[(size_t)tk * 8 + j] = f2bf(W[o * 256 + cb + j]);
    }
}

// ---- align: F[b][px][128c] = W @ concat(A,B), bf16 MFMA --------------------
__global__ __launch_bounds__(256, 2) void align_mfma_kernel(const ushort* __restrict__ A,
                                                            const ushort* __restrict__ Bv,
                                                            const ushort* __restrict__ Wf,
                                                            ushort* __restrict__ F) {
    __shared__ ushort Xs[2 * 128 * 8];
    const int b = blockIdx.y;
    const int px0 = blockIdx.x << 7;
    const int tid = threadIdx.x;
    const int wave = tid >> 6, lane = tid & 63;
    const int l31 = lane & 31, half = lane >> 5;

    f32x16 acc[4];
    #pragma unroll
    for (int mt = 0; mt < 4; mt++)
        #pragma unroll
        for (int r = 0; r < 16; r++) acc[mt][r] = 0.f;

    const int cg0 = tid >> 7, pxs0 = tid & 127;
    const int bfofs = (wave * 32 + l31) * 8 + half * 1024;

    for (int step = 0; step < 16; step++) {
        const ushort* src =
            (step < 8 ? A : Bv) + (((size_t)(b * 128 + (step & 7) * 16)) << 12) + px0;
        if (step) __syncthreads();
        #pragma unroll
        for (int q = 0; q < 2; q++) {
            int cg = cg0 + q * 2, px = pxs0;
            ushort v0 = src[((size_t)(cg * 4 + 0) << 12) + px];
            ushort v1 = src[((size_t)(cg * 4 + 1) << 12) + px];
            ushort v2 = src[((size_t)(cg * 4 + 2) << 12) + px];
            ushort v3 = src[((size_t)(cg * 4 + 3) << 12) + px];
            ushort4 pk = {v0, v1, v2, v3};
            *(ushort4*)&Xs[(cg >> 1) * 1024 + px * 8 + (cg & 1) * 4] = pk;
        }
        __syncthreads();
        bf16x8 bfrag = *(const bf16x8*)&Xs[bfofs];
        const bf16x8* wf = (const bf16x8*)(Wf + ((size_t)step * 4 * 64 + lane) * 8);
        #pragma unroll
        for (int mt = 0; mt < 4; mt++)
            acc[mt] = __builtin_amdgcn_mfma_f32_32x32x16_bf16(wf[mt * 64], bfrag, acc[mt], 0, 0, 0);
    }
    // epilogue: F[b][px][c]; o = mt*32 + half*4 + 8*g + i
    ushort* fp = F + ((size_t)(b * 4096 + px0 + wave * 32 + l31)) * 128;
    #pragma unroll
    for (int mt = 0; mt < 4; mt++) {
        #pragma unroll
        for (int g = 0; g < 4; g++) {
            ushort4 pk = {f2bf(acc[mt][g * 4 + 0]), f2bf(acc[mt][g * 4 + 1]),
                          f2bf(acc[mt][g * 4 + 2]), f2bf(acc[mt][g * 4 + 3])};
            *(ushort4*)(fp + mt * 32 + half * 4 + 8 * g) = pk;
        }
    }
}

// ---- combined up weight, A-frag order: Awt[s=tap*8+c16][mh(2)][mt(4)][lane][8]
// SEMANTIC op reorder for direct epilogue stores:
//   A-row arow=lane&31 in tile (mh,mt) represents output channel
//     o_sem = 32*(mt&1) + (arow&3) + 4*((arow>>3)&3) + 16*((arow>>2)&1)
//   at pixel-shuffle phase ph = 2*mh + (mt>>1)  (ry=mh, rx=mt>>1).
//   With D-row d=(r&3)+8*(r>>2)+4*half this makes lane channels = 32*(mt&1)+16*half + r
//   (16 CONSECUTIVE channels -> two 16B global stores per (mt,nt)).
__global__ __launch_bounds__(256) void wcomb_kernel(const float* __restrict__ w1,
                                                    const float* __restrict__ w2,
                                                    ushort* __restrict__ Awt) {
    int idx = blockIdx.x * 256 + threadIdx.x;  // < 294912
    int j = idx & 7;
    int lane = (idx >> 3) & 63;
    int mt = (idx >> 9) & 3;
    int mh = (idx >> 11) & 1;
    int s = idx >> 12;             // 0..71
    int tap = s >> 3, c16 = s & 7;
    int arow = lane & 31;
    int o_sem = (mt & 1) * 32 + (arow & 3) + 4 * ((arow >> 3) & 3) + 16 * ((arow >> 2) & 1);
    int ph = 2 * mh + (mt >> 1);
    int cin = c16 * 16 + (lane >> 5) * 8 + j;
    float acc = 0.f;
    #pragma unroll 4
    for (int c = 0; c < 128; c++)
        acc += w2[o_sem * 128 + c] * w1[((size_t)(c * 4 + ph) * 128 + cin) * 9 + tap];
    Awt[idx] = f2bf(acc);
}

// ---- re1 weight prep: Aw1[s(18)][lane(64)][8]  (16x16x32 A-frag order) -----
__global__ __launch_bounds__(256) void aw1prep_kernel(const float* __restrict__ w1,  // [8,64,3,3]
                                                      ushort* __restrict__ Aw1) {
    int idx = blockIdx.x * 256 + threadIdx.x;  // < 9216
    if (idx >= 9216) return;
    int j = idx & 7, lane = (idx >> 3) & 63, s = idx >> 9;
    int m = lane & 15, kq = lane >> 4;
    int tap = s >> 1, ch = s & 1;
    int cin = ch * 32 + kq * 8 + j;
    float v = (m < 8) ? w1[((size_t)(m * 64 + cin)) * 9 + tap] : 0.f;
    Aw1[idx] = f2bf(v);
}

// ---- re2 weight prep: Aw2[s(5)][mt(2)][lane(64)][8] (32x32x16 A-frag) ------
__global__ __launch_bounds__(256) void aw2prep_kernel(const float* __restrict__ w2,  // [64,8,3,3]
                                                      ushort* __restrict__ Aw2) {
    int idx = blockIdx.x * 256 + threadIdx.x;  // < 5120
    if (idx >= 5120) return;
    int j = idx & 7, lane = (idx >> 3) & 63, mt = (idx >> 9) & 1, s = idx >> 10;
    int m = mt * 32 + (lane & 31), half = lane >> 5;
    int k = s * 16 + half * 8 + j;
    int tap = k >> 3, c = k & 7;
    float v = (tap < 9) ? w2[((size_t)(m * 8 + c)) * 9 + tap] : 0.f;
    Aw2[idx] = f2bf(v);
}

// ------ up-conv: implicit GEMM 32x32x16 bf16, F[b,px,c] -> U[b,Y,X,64] ------
// OCCUPANCY FIX: 512 threads / 8 waves, acc[2][2] = 64 AGPR per wave,
// __launch_bounds__(512,4) -> 4 waves/SIMD (2 blocks/CU, LDS 2x46KB = 92KB).
// Wave (mh = w>>2, bmt = (w>>1)&1, nh = w&1) owns op-quarter x px-half.
// A: distance-2 global ping-pong; B: distance-2 swizzled-LDS ping-pong.
// Direct-store epilogue (wcomb semantic reorder). No barriers in main loop.
__global__ __launch_bounds__(512, 4) void up_mfma_kernel(const ushort* __restrict__ F,
                                                         const ushort* __restrict__ Awt,
                                                         ushort* __restrict__ U) {
    __shared__ ushort Xs[180 * 128];  // 46080 B
    const int b = blockIdx.y;
    const int tr = blockIdx.x >> 3, tc = blockIdx.x & 7;
    const int tid = threadIdx.x;
    const int wave = tid >> 6, lane = tid & 63;
    const int l31 = lane & 31, half = lane >> 5;
    const int mh = wave >> 2, bmt = (wave >> 1) & 1, nh = wave & 1;

    // stage whole 18x10 halo x 128c; unit q stored at slot q ^ (px&7)
    for (int idx = tid; idx < 2880; idx += 512) {
        int px = idx >> 4, q = idx & 15;
        int r = px / 10, c = px - r * 10;
        int gh = tr * 16 - 1 + r, gw = tc * 8 - 1 + c;
        int4 v = {0, 0, 0, 0};
        if ((unsigned)gh < 64u && (unsigned)gw < 64u)
            v = *(const int4*)(F + ((size_t)(b * 4096 + gh * 64 + gw)) * 128 + q * 8);
        *(int4*)&Xs[px * 128 + ((q ^ (px & 7)) << 3)] = v;
    }
    __syncthreads();

    f32x16 acc[2][2];
    #pragma unroll
    for (int mt = 0; mt < 2; mt++)
        #pragma unroll
        for (int nt = 0; nt < 2; nt++)
            #pragma unroll
            for (int r = 0; r < 16; r++) acc[mt][nt][r] = 0.f;

    int xpos[2];
    #pragma unroll
    for (int nt = 0; nt < 2; nt++) {
        int pxl = nh * 64 + nt * 32 + l31;
        xpos[nt] = (pxl >> 3) * 10 + (pxl & 7);
    }

    // A stream: element offset (s*8 + mh*4 + bmt*2 + mtl)*512 + lane*8
    const ushort* abase = Awt + (size_t)(mh * 4 + bmt * 2) * 512 + lane * 8;

    #define LDA(ss, mtl) (*(const bf16x8*)(abase + (size_t)(ss) * 4096 + (mtl) * 512))
    #define LDB(ss, nt) ({                                                   \
        int tap_ = (ss) >> 3, c16_ = (ss) & 7;                               \
        int ky_ = (tap_ * 11) >> 5;  /* tap/3 for 0..8 */                    \
        int kx_ = tap_ - ky_ * 3;                                            \
        int p_ = xpos[nt] + ky_ * 10 + kx_;                                  \
        int qq_ = c16_ * 2 + half;                                           \
        *(const bf16x8*)&Xs[p_ * 128 + ((qq_ ^ (p_ & 7)) << 3)];             \
    })

    bf16x8 A0[2], A1[2], B0[2], B1[2];
    A0[0] = LDA(0, 0); A0[1] = LDA(0, 1);
    A1[0] = LDA(1, 0); A1[1] = LDA(1, 1);
    B0[0] = LDB(0, 0); B0[1] = LDB(0, 1);
    B1[0] = LDB(1, 0); B1[1] = LDB(1, 1);

    #define SUBSTEP(ASET, BSET, sn)                                                  \
    {                                                                                \
        _Pragma("unroll")                                                            \
        for (int mt = 0; mt < 2; mt++) {                                             \
            acc[mt][0] = __builtin_amdgcn_mfma_f32_32x32x16_bf16(ASET[mt], BSET[0], acc[mt][0], 0, 0, 0); \
            acc[mt][1] = __builtin_amdgcn_mfma_f32_32x32x16_bf16(ASET[mt], BSET[1], acc[mt][1], 0, 0, 0); \
        }                                                                            \
        ASET[0] = LDA(sn, 0); ASET[1] = LDA(sn, 1);                                  \
        BSET[0] = LDB(sn, 0); BSET[1] = LDB(sn, 1);                                  \
    }

    #pragma unroll 2
    for (int s = 0; s < 70; s += 2) {
        SUBSTEP(A0, B0, s + 2)
        int s3 = (s + 3 < 72) ? s + 3 : 0;
        SUBSTEP(A1, B1, s3)
    }
    // s = 70, 71 (prefetches above were clamped; just consume)
    #pragma unroll
    for (int mt = 0; mt < 2; mt++) {
        acc[mt][0] = __builtin_amdgcn_mfma_f32_32x32x16_bf16(A0[mt], B0[0], acc[mt][0], 0, 0, 0);
        acc[mt][1] = __builtin_amdgcn_mfma_f32_32x32x16_bf16(A0[mt], B0[1], acc[mt][1], 0, 0, 0);
    }
    #pragma unroll
    for (int mt = 0; mt < 2; mt++) {
        acc[mt][0] = __builtin_amdgcn_mfma_f32_32x32x16_bf16(A1[mt], B1[0], acc[mt][0], 0, 0, 0);
        acc[mt][1] = __builtin_amdgcn_mfma_f32_32x32x16_bf16(A1[mt], B1[1], acc[mt][1], 0, 0, 0);
    }
    #undef SUBSTEP
    #undef LDA
    #undef LDB

    // direct epilogue: per (mtl,nt) two 16B stores of 8 consecutive channels
    // global mt = bmt*2 + mtl; Y = 2*(tr*16+h)+mh, X = 2*(tc*8+w)+bmt,
    // ch = 32*mtl + 16*half + r
    #pragma unroll
    for (int nt = 0; nt < 2; nt++) {
        int pxl = nh * 64 + nt * 32 + l31;
        int Y = 2 * (tr * 16 + (pxl >> 3)) + mh;
        int X = 2 * (tc * 8 + (pxl & 7)) + bmt;
        #pragma unroll
        for (int mt = 0; mt < 2; mt++) {
            ushort* up = U + ((size_t)((b * 128 + Y) * 128 + X)) * 64
                       + mt * 32 + half * 16;
            us8 p0, p1;
            #pragma unroll
            for (int i = 0; i < 8; i++) {
                p0[i] = f2bf(acc[mt][nt][i]);
                p1[i] = f2bf(acc[mt][nt][8 + i]);
            }
            *(us8*)up = p0;
            *(us8*)(up + 8) = p1;
        }
    }
}

// ------ re1: conv3x3(U,re_w1)+relu via 16x16x32 MFMA -> R1[b,Y,X,8] ---------
__global__ __launch_bounds__(256, 2) void re1_kernel(const ushort* __restrict__ U,
                                                     const ushort* __restrict__ Aw1,
                                                     ushort* __restrict__ R1) {
    __shared__ ushort Xs[324 * 72];  // 46656 B
    __shared__ ushort As[18 * 64 * 8];
    const int b = blockIdx.y;
    const int ty = blockIdx.x >> 3, tx = blockIdx.x & 7;
    const int tid = threadIdx.x;
    const int wave = tid >> 6, lane = tid & 63;
    const int m16 = lane & 15, kq = lane >> 4;

    for (int idx = tid; idx < 1152; idx += 256)
        *(int4*)&As[idx * 8] = *(const int4*)(Aw1 + (size_t)idx * 8);
    for (int idx = tid; idx < 2592; idx += 256) {
        int px = idx >> 3, q = idx & 7;
        int r = px / 18, c = px - r * 18;
        int gY = ty * 16 - 1 + r, gX = tx * 16 - 1 + c;
        int4 v = {0, 0, 0, 0};
        if ((unsigned)gY < 128u && (unsigned)gX < 128u)
            v = *(const int4*)(U + ((size_t)((b * 128 + gY) * 128 + gX)) * 64 + q * 8);
        *(int4*)&Xs[px * 72 + q * 8] = v;
    }
    __syncthreads();

    f32x4 acc[4];
    #pragma unroll
    for (int nt = 0; nt < 4; nt++)
        #pragma unroll
        for (int r = 0; r < 4; r++) acc[nt][r] = 0.f;

    #pragma unroll 1
    for (int s = 0; s < 18; s++) {
        bf16x8 a = *(const bf16x8*)&As[(s * 64 + lane) * 8];
        int tap = s >> 1, ch = s & 1;
        int ky = tap / 3, kx = tap - ky * 3;
        int xo = (ky * 18 + kx) * 72 + ch * 32 + kq * 8;
        #pragma unroll
        for (int nt = 0; nt < 4; nt++) {
            int row = wave * 4 + nt;
            bf16x8 bv = *(const bf16x8*)&Xs[(row * 18 + m16) * 72 + xo];
            acc[nt] = __builtin_amdgcn_mfma_f32_16x16x32_bf16(a, bv, acc[nt], 0, 0, 0);
        }
    }
    if (kq < 2) {
        #pragma unroll
        for (int nt = 0; nt < 4; nt++) {
            int gY = ty * 16 + wave * 4 + nt, gX = tx * 16 + m16;
            ushort4 pk = {f2bf(fmaxf(acc[nt][0], 0.f)), f2bf(fmaxf(acc[nt][1], 0.f)),
                          f2bf(fmaxf(acc[nt][2], 0.f)), f2bf(fmaxf(acc[nt][3], 0.f))};
            *(ushort4*)(R1 + ((size_t)((b * 128 + gY) * 128 + gX)) * 8 + kq * 4) = pk;
        }
    }
}

// ------ re2: conv3x3(R1,re_w2) + up  via 32x32x16 MFMA -> out f32 planar ----
__global__ __launch_bounds__(256, 2) void re2_kernel(const ushort* __restrict__ R1,
                                                     const ushort* __restrict__ U,
                                                     const ushort* __restrict__ Aw2,
                                                     float* __restrict__ out) {
    __shared__ ushort Xs[324 * 8];   // 5184 B
    __shared__ ushort As[5 * 2 * 64 * 8];
    __shared__ ushort Us[256 * 68];  // 34816 B
    const int b = blockIdx.y;
    const int ty = blockIdx.x >> 3, tx = blockIdx.x & 7;
    const int tid = threadIdx.x;
    const int wave = tid >> 6, lane = tid & 63;
    const int l31 = lane & 31, half = lane >> 5;

    for (int idx = tid; idx < 640; idx += 256)
        *(int4*)&As[idx * 8] = *(const int4*)(Aw2 + (size_t)idx * 8);
    for (int idx = tid; idx < 324; idx += 256) {
        int r = idx / 18, c = idx - r * 18;
        int gY = ty * 16 - 1 + r, gX = tx * 16 - 1 + c;
        int4 v = {0, 0, 0, 0};
        if ((unsigned)gY < 128u && (unsigned)gX < 128u)
            v = *(const int4*)(R1 + ((size_t)((b * 128 + gY) * 128 + gX)) * 8);
        *(int4*)&Xs[idx * 8] = v;
    }
    for (int idx = tid; idx < 2048; idx += 256) {
        int px = idx >> 3, q = idx & 7;
        int gY = ty * 16 + (px >> 4), gX = tx * 16 + (px & 15);
        const ushort* s = U + ((size_t)((b * 128 + gY) * 128 + gX)) * 64 + q * 8;
        ushort4 v0 = *(const ushort4*)s;
        ushort4 v1 = *(const ushort4*)(s + 4);
        *(ushort4*)&Us[px * 68 + q * 8] = v0;
        *(ushort4*)&Us[px * 68 + q * 8 + 4] = v1;
    }
    __syncthreads();

    f32x16 acc[2][2];
    #pragma unroll
    for (int mt = 0; mt < 2; mt++)
        #pragma unroll
        for (int nt = 0; nt < 2; nt++)
            #pragma unroll
            for (int r = 0; r < 16; r++) acc[mt][nt][r] = 0.f;

    #pragma unroll
    for (int s = 0; s < 5; s++) {
        bf16x8 a0 = *(const bf16x8*)&As[((s * 2 + 0) * 64 + lane) * 8];
        bf16x8 a1 = *(const bf16x8*)&As[((s * 2 + 1) * 64 + lane) * 8];
        int t = 2 * s + half;
        if (t > 8) t = 8;  // A is zero there
        int ky = t / 3, kx = t - ky * 3;
        #pragma unroll
        for (int nt = 0; nt < 2; nt++) {
            int pxl = wave * 64 + nt * 32 + l31;
            int row = pxl >> 4, col = pxl & 15;
            bf16x8 bv = *(const bf16x8*)&Xs[((row + ky) * 18 + col + kx) * 8];
            acc[0][nt] = __builtin_amdgcn_mfma_f32_32x32x16_bf16(a0, bv, acc[0][nt], 0, 0, 0);
            acc[1][nt] = __builtin_amdgcn_mfma_f32_32x32x16_bf16(a1, bv, acc[1][nt], 0, 0, 0);
        }
    }
    #pragma unroll
    for (int mt = 0; mt < 2; mt++) {
        #pragma unroll
        for (int nt = 0; nt < 2; nt++) {
            int pxl = wave * 64 + nt * 32 + l31;
            int gY = ty * 16 + (pxl >> 4), gX = tx * 16 + (pxl & 15);
            #pragma unroll
            for (int r = 0; r < 16; r++) {
                int o = mt * 32 + (r & 3) + 8 * (r >> 2) + 4 * half;
                float v = acc[mt][nt][r] + bf2f(Us[pxl * 68 + o]);
                out[((size_t)(b * 64 + o) * 128 + gY) * 128 + gX] = v;
            }
        }
    }
}

extern "C" void kernel_launch(void* const* d_in, const int* in_sizes, int n_in,
                              void* d_out, int out_size, void* d_ws, size_t ws_size,
                              hipStream_t stream) {
    const float* x1      = (const float*)d_in[0];
    const float* x2      = (const float*)d_in[1];
    const float* d1_w1   = (const float*)d_in[2];
    const float* d1_w2   = (const float*)d_in[3];
    const float* d2_w1   = (const float*)d_in[4];
    const float* d2_w2   = (const float*)d_in[5];
    const float* align_w = (const float*)d_in[6];
    const float* up_w1   = (const float*)d_in[7];
    const float* up_w2   = (const float*)d_in[8];
    const float* re_w1   = (const float*)d_in[9];
    const float* re_w2   = (const float*)d_in[10];
    float* out = (float*)d_out;
    float* ws  = (float*)d_ws;

    float*  pooled = ws + OFF_POOLED;
    float*  wkb    = ws + OFF_WK;
    ushort* Awt    = (ushort*)(ws + OFF_WT);
    ushort* Wf     = (ushort*)(ws + OFF_WF);
    ushort* Aw1    = (ushort*)(ws + OFF_AW1);
    ushort* Aw2    = (ushort*)(ws + OFF_AW2);
    ushort* bufT   = (ushort*)(ws + OFF_T);
    ushort* R1     = (ushort*)(ws + OFF_T);   // alias (bufT dead by re1)
    ushort* bufAB  = (ushort*)(ws + OFF_AB);
    ushort* bufU   = (ushort*)(ws + OFF_AB);  // alias (bufAB dead after align)
    ushort* F      = (ushort*)(ws + OFF_F);

    wcomb_kernel<<<1152, 256, 0, stream>>>(up_w1, up_w2, Awt);
    awprep_kernel<<<1, 256, 0, stream>>>(align_w, Wf);
    aw1prep_kernel<<<36, 256, 0, stream>>>(re_w1, Aw1);
    aw2prep_kernel<<<20, 256, 0, stream>>>(re_w2, Aw2);

    pool_both_kernel<<<4096, 256, 0, stream>>>(x1, x2, pooled);
    wk_kernel<<<32, 128, 0, stream>>>(pooled, d1_w1, d1_w2, wkb);
    dsc1_kernel<<<4096, 256, 0, stream>>>(x1, x2, wkb, bufT, pooled);
    wk_kernel<<<32, 128, 0, stream>>>(pooled, d2_w1, d2_w2, wkb);
    dsc2_kernel<<<4096, 256, 0, stream>>>(bufT, wkb, bufAB);

    align_mfma_kernel<<<dim3(32, 16), 256, 0, stream>>>(bufAB, bufAB + 8388608, Wf, F);
    up_mfma_kernel<<<dim3(32, 16), 512, 0, stream>>>(F, Awt, bufU);
    re1_kernel<<<dim3(64, 16), 256, 0, stream>>>(bufU, Aw1, R1);
    re2_kernel<<<dim3(64, 16), 256, 0, stream>>>(R1, bufU, Aw2, out);
}

// Round 7
// 328.313 us; speedup vs baseline: 1.0700x; 1.0242x over previous
//
#include <hip/hip_runtime.h>
#include <math.h>

typedef unsigned short ushort;
typedef short bf16x8 __attribute__((ext_vector_type(8)));
typedef ushort us8 __attribute__((ext_vector_type(8)));
typedef float f32x16 __attribute__((ext_vector_type(16)));
typedef float f32x4 __attribute__((ext_vector_type(4)));

// ---------------- workspace layout (float elements) ----------------
static const size_t OFF_POOLED = 0;         // 4096 f (2 inputs x 2048)
static const size_t OFF_WK     = 4096;      // pooled2 (4096 f)
static const size_t OFF_WT     = 40960;     // Awt 294912 sh = 147456 f
static const size_t OFF_WF     = 188416;    // Wf 32768 sh = 16384 f
static const size_t OFF_AW1    = 204800;    // 9216 sh = 4608 f
static const size_t OFF_AW2    = 209408;    // 5120 sh = 2560 f
static const size_t OFF_T      = 262144;    // bufT 2x8M sh = 8388608 f ; R1 aliases
static const size_t OFF_AB     = 8650752;   // bufAB 2x8M sh = 8388608 f ; bufU aliases
static const size_t OFF_F      = 17039360;  // F 8388608 sh = 4194304 f
// total 21233664 f = 85 MB

static __device__ __forceinline__ ushort f2bf(float f) {
    unsigned int u = __builtin_bit_cast(unsigned int, f);
    u += 0x7FFF + ((u >> 16) & 1);
    return (ushort)(u >> 16);
}
static __device__ __forceinline__ float bf2f(ushort u) {
    return __builtin_bit_cast(float, ((unsigned int)u) << 16);
}

// ---- head: pool (blocks 0..4095) + wcomb (4096..5247) + awprep (5248)
//      + aw1prep (5249..5284) + aw2prep (5285..5304), one launch ------------
__global__ __launch_bounds__(256) void head_kernel(const float* __restrict__ x1,
                                                   const float* __restrict__ x2,
                                                   float* __restrict__ pooled,
                                                   const float* __restrict__ up_w1,
                                                   const float* __restrict__ up_w2,
                                                   ushort* __restrict__ Awt,
                                                   const float* __restrict__ align_w,
                                                   ushort* __restrict__ Wf,
                                                   const float* __restrict__ re_w1,
                                                   ushort* __restrict__ Aw1,
                                                   const float* __restrict__ re_w2,
                                                   ushort* __restrict__ Aw2) {
    const int bid = blockIdx.x;
    const int t = threadIdx.x;
    if (bid < 4096) {
        // ---- pool ----
        int bc = bid;
        const float* x = (bc >> 11) ? x2 : x1;
        const float4* p = (const float4*)(x + (size_t)(bc & 2047) * 4096);
        float s = 0.f;
        for (int i = t; i < 1024; i += 256) {
            float4 v = p[i];
            s += v.x + v.y + v.z + v.w;
        }
        #pragma unroll
        for (int off = 32; off; off >>= 1) s += __shfl_down(s, off);
        __shared__ float r4[4];
        if ((t & 63) == 0) r4[t >> 6] = s;
        __syncthreads();
        if (t == 0) pooled[bc] = (r4[0] + r4[1] + r4[2] + r4[3]) * (1.f / 4096.f);
    } else if (bid < 5248) {
        // ---- wcomb: combined up weight, semantic op reorder ----
        int idx = (bid - 4096) * 256 + t;  // < 294912
        int j = idx & 7;
        int lane = (idx >> 3) & 63;
        int mt = (idx >> 9) & 3;
        int mh = (idx >> 11) & 1;
        int s = idx >> 12;             // 0..71
        int tap = s >> 3, c16 = s & 7;
        int arow = lane & 31;
        int o_sem = (mt & 1) * 32 + (arow & 3) + 4 * ((arow >> 3) & 3) + 16 * ((arow >> 2) & 1);
        int ph = 2 * mh + (mt >> 1);
        int cin = c16 * 16 + (lane >> 5) * 8 + j;
        float acc = 0.f;
        #pragma unroll 4
        for (int c = 0; c < 128; c++)
            acc += up_w2[o_sem * 128 + c] * up_w1[((size_t)(c * 4 + ph) * 128 + cin) * 9 + tap];
        Awt[idx] = f2bf(acc);
    } else if (bid == 5248) {
        // ---- awprep: Wf [step(16)][mt(4)][lane(64)][8] ----
        #pragma unroll 1
        for (int i = 0; i < 16; i++) {
            int tk = t + (i << 8);
            int step = tk >> 8, mt = (tk >> 6) & 3, lane = tk & 63;
            int o = mt * 32 + (lane & 31);
            int cb = step * 16 + (lane >> 5) * 8;
            #pragma unroll
            for (int j = 0; j < 8; j++) Wf[(size_t)tk * 8 + j] = f2bf(align_w[o * 256 + cb + j]);
        }
    } else if (bid < 5285) {
        // ---- aw1prep ----
        int idx = (bid - 5249) * 256 + t;  // < 9216
        if (idx < 9216) {
            int j = idx & 7, lane = (idx >> 3) & 63, s = idx >> 9;
            int m = lane & 15, kq = lane >> 4;
            int tap = s >> 1, ch = s & 1;
            int cin = ch * 32 + kq * 8 + j;
            float v = (m < 8) ? re_w1[((size_t)(m * 64 + cin)) * 9 + tap] : 0.f;
            Aw1[idx] = f2bf(v);
        }
    } else {
        // ---- aw2prep ----
        int idx = (bid - 5285) * 256 + t;  // < 5120
        if (idx < 5120) {
            int j = idx & 7, lane = (idx >> 3) & 63, mt = (idx >> 9) & 1, s = idx >> 10;
            int m = mt * 32 + (lane & 31), half = lane >> 5;
            int k = s * 16 + half * 8 + j;
            int tap = k >> 3, c = k & 7;
            float v = (tap < 9) ? re_w2[((size_t)(m * 8 + c)) * 9 + tap] : 0.f;
            Aw2[idx] = f2bf(v);
        }
    }
}

// -------- dsc1: f32 in, bf16 out, relu+pool, wk computed inline -------------
__global__ __launch_bounds__(256) void dsc1_kernel(const float* __restrict__ x1,
                                                   const float* __restrict__ x2,
                                                   const float* __restrict__ pooled,
                                                   const float* __restrict__ w1,
                                                   const float* __restrict__ w2,
                                                   ushort* __restrict__ y,
                                                   float* __restrict__ pooled2) {
    int bc = blockIdx.x;  // 4096
    const float* xp = ((bc >> 11) ? x2 : x1) + (size_t)(bc & 2047) * 4096;
    ushort* yp = y + (size_t)bc * 4096;
    __shared__ float tile[66 * 66];
    __shared__ float r4[4];
    __shared__ float sp[128];
    __shared__ float sh[16];
    __shared__ float lgs[9];
    int t = threadIdx.x;
    if (t < 128) sp[t] = pooled[(bc >> 7) * 128 + t];
    for (int i = t; i < 66 * 66; i += 256) tile[i] = 0.f;
    __syncthreads();
    // gelu(pooled @ w1^T) by lanes 0..15, overlapped with tile fill
    if (t < 16) {
        float a = 0.f;
        #pragma unroll 4
        for (int c = 0; c < 128; c++) a += w1[t * 128 + c] * sp[c];
        sh[t] = 0.5f * a * (1.f + erff(a * 0.70710678118654752f));
    }
    const float4* xp4 = (const float4*)xp;
    for (int i = t; i < 1024; i += 256) {
        float4 v = xp4[i];
        int h = i >> 4, w = (i & 15) * 4;
        float* d = &tile[(h + 1) * 66 + w + 1];
        d[0] = v.x; d[1] = v.y; d[2] = v.z; d[3] = v.w;
    }
    __syncthreads();
    if (t < 9) {
        float a = 0.f;
        const float* wr = w2 + (size_t)((bc & 127) * 9 + t) * 16;
        #pragma unroll
        for (int r = 0; r < 16; r++) a += wr[r] * sh[r];
        lgs[t] = a;
    }
    __syncthreads();
    float kk[9];
    {
        float m = -INFINITY;
        #pragma unroll
        for (int k = 0; k < 9; k++) m = fmaxf(m, lgs[k]);
        float se = 0.f;
        #pragma unroll
        for (int k = 0; k < 9; k++) { kk[k] = expf(lgs[k] - m); se += kk[k]; }
        float inv = 1.f / se;
        #pragma unroll
        for (int k = 0; k < 9; k++) kk[k] *= inv;
    }
    float psum = 0.f;
    for (int i = t * 2; i < 4096; i += 512) {
        int h = i >> 6, w = i & 63;
        const float* c = &tile[h * 66 + w];
        float v0 = kk[0]*c[0] + kk[1]*c[1] + kk[2]*c[2]
                 + kk[3]*c[66] + kk[4]*c[67] + kk[5]*c[68]
                 + kk[6]*c[132] + kk[7]*c[133] + kk[8]*c[134] + c[67];
        float v1 = kk[0]*c[1] + kk[1]*c[2] + kk[2]*c[3]
                 + kk[3]*c[67] + kk[4]*c[68] + kk[5]*c[69]
                 + kk[6]*c[133] + kk[7]*c[134] + kk[8]*c[135] + c[68];
        v0 = fmaxf(v0, 0.f); v1 = fmaxf(v1, 0.f);
        psum += v0 + v1;
        ushort2 pk = {f2bf(v0), f2bf(v1)};
        *(ushort2*)&yp[i] = pk;
    }
    #pragma unroll
    for (int off = 32; off; off >>= 1) psum += __shfl_down(psum, off);
    if ((t & 63) == 0) r4[t >> 6] = psum;
    __syncthreads();
    if (t == 0) pooled2[bc] = (r4[0] + r4[1] + r4[2] + r4[3]) * (1.f / 4096.f);
}

// -------- dsc2: bf16 in, bf16 out, wk computed inline -----------------------
__global__ __launch_bounds__(256) void dsc2_kernel(const ushort* __restrict__ x,
                                                   const float* __restrict__ pooled,
                                                   const float* __restrict__ w1,
                                                   const float* __restrict__ w2,
                                                   ushort* __restrict__ y) {
    int bc = blockIdx.x;  // 4096
    const ushort* xp = x + (size_t)bc * 4096;
    ushort* yp = y + (size_t)bc * 4096;
    __shared__ float tile[66 * 66];
    __shared__ float sp[128];
    __shared__ float sh[16];
    __shared__ float lgs[9];
    int t = threadIdx.x;
    if (t < 128) sp[t] = pooled[(bc >> 7) * 128 + t];
    for (int i = t; i < 66 * 66; i += 256) tile[i] = 0.f;
    __syncthreads();
    if (t < 16) {
        float a = 0.f;
        #pragma unroll 4
        for (int c = 0; c < 128; c++) a += w1[t * 128 + c] * sp[c];
        sh[t] = 0.5f * a * (1.f + erff(a * 0.70710678118654752f));
    }
    for (int i = t; i < 512; i += 256) {
        int4 raw = *(const int4*)&xp[i * 8];
        const ushort* u = (const ushort*)&raw;
        int h = i >> 3, w = (i & 7) * 8;
        float* d = &tile[(h + 1) * 66 + w + 1];
        #pragma unroll
        for (int j = 0; j < 8; j++) d[j] = bf2f(u[j]);
    }
    __syncthreads();
    if (t < 9) {
        float a = 0.f;
        const float* wr = w2 + (size_t)((bc & 127) * 9 + t) * 16;
        #pragma unroll
        for (int r = 0; r < 16; r++) a += wr[r] * sh[r];
        lgs[t] = a;
    }
    __syncthreads();
    float kk[9];
    {
        float m = -INFINITY;
        #pragma unroll
        for (int k = 0; k < 9; k++) m = fmaxf(m, lgs[k]);
        float se = 0.f;
        #pragma unroll
        for (int k = 0; k < 9; k++) { kk[k] = expf(lgs[k] - m); se += kk[k]; }
        float inv = 1.f / se;
        #pragma unroll
        for (int k = 0; k < 9; k++) kk[k] *= inv;
    }
    for (int i = t * 2; i < 4096; i += 512) {
        int h = i >> 6, w = i & 63;
        const float* c = &tile[h * 66 + w];
        float v0 = kk[0]*c[0] + kk[1]*c[1] + kk[2]*c[2]
                 + kk[3]*c[66] + kk[4]*c[67] + kk[5]*c[68]
                 + kk[6]*c[132] + kk[7]*c[133] + kk[8]*c[134] + c[67];
        float v1 = kk[0]*c[1] + kk[1]*c[2] + kk[2]*c[3]
                 + kk[3]*c[67] + kk[4]*c[68] + kk[5]*c[69]
                 + kk[6]*c[133] + kk[7]*c[134] + kk[8]*c[135] + c[68];
        ushort2 pk = {f2bf(v0), f2bf(v1)};
        *(ushort2*)&yp[i] = pk;
    }
}

// ---- align: F[b][px][128c] = W @ concat(A,B), bf16 MFMA --------------------
__global__ __launch_bounds__(256, 2) void align_mfma_kernel(const ushort* __restrict__ A,
                                                            const ushort* __restrict__ Bv,
                                                            const ushort* __restrict__ Wf,
                                                            ushort* __restrict__ F) {
    __shared__ ushort Xs[2 * 128 * 8];
    const int b = blockIdx.y;
    const int px0 = blockIdx.x << 7;
    const int tid = threadIdx.x;
    const int wave = tid >> 6, lane = tid & 63;
    const int l31 = lane & 31, half = lane >> 5;

    f32x16 acc[4];
    #pragma unroll
    for (int mt = 0; mt < 4; mt++)
        #pragma unroll
        for (int r = 0; r < 16; r++) acc[mt][r] = 0.f;

    const int cg0 = tid >> 7, pxs0 = tid & 127;
    const int bfofs = (wave * 32 + l31) * 8 + half * 1024;

    for (int step = 0; step < 16; step++) {
        const ushort* src =
            (step < 8 ? A : Bv) + (((size_t)(b * 128 + (step & 7) * 16)) << 12) + px0;
        if (step) __syncthreads();
        #pragma unroll
        for (int q = 0; q < 2; q++) {
            int cg = cg0 + q * 2, px = pxs0;
            ushort v0 = src[((size_t)(cg * 4 + 0) << 12) + px];
            ushort v1 = src[((size_t)(cg * 4 + 1) << 12) + px];
            ushort v2 = src[((size_t)(cg * 4 + 2) << 12) + px];
            ushort v3 = src[((size_t)(cg * 4 + 3) << 12) + px];
            ushort4 pk = {v0, v1, v2, v3};
            *(ushort4*)&Xs[(cg >> 1) * 1024 + px * 8 + (cg & 1) * 4] = pk;
        }
        __syncthreads();
        bf16x8 bfrag = *(const bf16x8*)&Xs[bfofs];
        const bf16x8* wf = (const bf16x8*)(Wf + ((size_t)step * 4 * 64 + lane) * 8);
        #pragma unroll
        for (int mt = 0; mt < 4; mt++)
            acc[mt] = __builtin_amdgcn_mfma_f32_32x32x16_bf16(wf[mt * 64], bfrag, acc[mt], 0, 0, 0);
    }
    // epilogue: F[b][px][c]; o = mt*32 + half*4 + 8*g + i
    ushort* fp = F + ((size_t)(b * 4096 + px0 + wave * 32 + l31)) * 128;
    #pragma unroll
    for (int mt = 0; mt < 4; mt++) {
        #pragma unroll
        for (int g = 0; g < 4; g++) {
            ushort4 pk = {f2bf(acc[mt][g * 4 + 0]), f2bf(acc[mt][g * 4 + 1]),
                          f2bf(acc[mt][g * 4 + 2]), f2bf(acc[mt][g * 4 + 3])};
            *(ushort4*)(fp + mt * 32 + half * 4 + 8 * g) = pk;
        }
    }
}

// ------ up-conv: implicit GEMM 32x32x16 bf16, F[b,px,c] -> U[b,Y,X,64] ------
// 512 threads / 8 waves, acc[2][2] = 64 AGPR per wave, (512,4) -> 4 waves/SIMD.
// Wave (mh = w>>2, bmt = (w>>1)&1, nh = w&1) owns op-quarter x px-half.
// A: distance-2 global ping-pong; B: distance-2 swizzled-LDS ping-pong.
// Direct-store epilogue (wcomb semantic reorder). No barriers in main loop.
__global__ __launch_bounds__(512, 4) void up_mfma_kernel(const ushort* __restrict__ F,
                                                         const ushort* __restrict__ Awt,
                                                         ushort* __restrict__ U) {
    __shared__ ushort Xs[180 * 128];  // 46080 B
    const int b = blockIdx.y;
    const int tr = blockIdx.x >> 3, tc = blockIdx.x & 7;
    const int tid = threadIdx.x;
    const int wave = tid >> 6, lane = tid & 63;
    const int l31 = lane & 31, half = lane >> 5;
    const int mh = wave >> 2, bmt = (wave >> 1) & 1, nh = wave & 1;

    // stage whole 18x10 halo x 128c; unit q stored at slot q ^ (px&7)
    for (int idx = tid; idx < 2880; idx += 512) {
        int px = idx >> 4, q = idx & 15;
        int r = px / 10, c = px - r * 10;
        int gh = tr * 16 - 1 + r, gw = tc * 8 - 1 + c;
        int4 v = {0, 0, 0, 0};
        if ((unsigned)gh < 64u && (unsigned)gw < 64u)
            v = *(const int4*)(F + ((size_t)(b * 4096 + gh * 64 + gw)) * 128 + q * 8);
        *(int4*)&Xs[px * 128 + ((q ^ (px & 7)) << 3)] = v;
    }
    __syncthreads();

    f32x16 acc[2][2];
    #pragma unroll
    for (int mt = 0; mt < 2; mt++)
        #pragma unroll
        for (int nt = 0; nt < 2; nt++)
            #pragma unroll
            for (int r = 0; r < 16; r++) acc[mt][nt][r] = 0.f;

    int xpos[2];
    #pragma unroll
    for (int nt = 0; nt < 2; nt++) {
        int pxl = nh * 64 + nt * 32 + l31;
        xpos[nt] = (pxl >> 3) * 10 + (pxl & 7);
    }

    // A stream: element offset (s*8 + mh*4 + bmt*2 + mtl)*512 + lane*8
    const ushort* abase = Awt + (size_t)(mh * 4 + bmt * 2) * 512 + lane * 8;

    #define LDA(ss, mtl) (*(const bf16x8*)(abase + (size_t)(ss) * 4096 + (mtl) * 512))
    #define LDB(ss, nt) ({                                                   \
        int tap_ = (ss) >> 3, c16_ = (ss) & 7;                               \
        int ky_ = (tap_ * 11) >> 5;  /* tap/3 for 0..8 */                    \
        int kx_ = tap_ - ky_ * 3;                                            \
        int p_ = xpos[nt] + ky_ * 10 + kx_;                                  \
        int qq_ = c16_ * 2 + half;                                           \
        *(const bf16x8*)&Xs[p_ * 128 + ((qq_ ^ (p_ & 7)) << 3)];             \
    })

    bf16x8 A0[2], A1[2], B0[2], B1[2];
    A0[0] = LDA(0, 0); A0[1] = LDA(0, 1);
    A1[0] = LDA(1, 0); A1[1] = LDA(1, 1);
    B0[0] = LDB(0, 0); B0[1] = LDB(0, 1);
    B1[0] = LDB(1, 0); B1[1] = LDB(1, 1);

    #define SUBSTEP(ASET, BSET, sn)                                                  \
    {                                                                                \
        _Pragma("unroll")                                                            \
        for (int mt = 0; mt < 2; mt++) {                                             \
            acc[mt][0] = __builtin_amdgcn_mfma_f32_32x32x16_bf16(ASET[mt], BSET[0], acc[mt][0], 0, 0, 0); \
            acc[mt][1] = __builtin_amdgcn_mfma_f32_32x32x16_bf16(ASET[mt], BSET[1], acc[mt][1], 0, 0, 0); \
        }                                                                            \
        ASET[0] = LDA(sn, 0); ASET[1] = LDA(sn, 1);                                  \
        BSET[0] = LDB(sn, 0); BSET[1] = LDB(sn, 1);                                  \
    }

    #pragma unroll 2
    for (int s = 0; s < 70; s += 2) {
        SUBSTEP(A0, B0, s + 2)
        int s3 = (s + 3 < 72) ? s + 3 : 0;
        SUBSTEP(A1, B1, s3)
    }
    // s = 70, 71 (prefetches above were clamped; just consume)
    #pragma unroll
    for (int mt = 0; mt < 2; mt++) {
        acc[mt][0] = __builtin_amdgcn_mfma_f32_32x32x16_bf16(A0[mt], B0[0], acc[mt][0], 0, 0, 0);
        acc[mt][1] = __builtin_amdgcn_mfma_f32_32x32x16_bf16(A0[mt], B0[1], acc[mt][1], 0, 0, 0);
    }
    #pragma unroll
    for (int mt = 0; mt < 2; mt++) {
        acc[mt][0] = __builtin_amdgcn_mfma_f32_32x32x16_bf16(A1[mt], B1[0], acc[mt][0], 0, 0, 0);
        acc[mt][1] = __builtin_amdgcn_mfma_f32_32x32x16_bf16(A1[mt], B1[1], acc[mt][1], 0, 0, 0);
    }
    #undef SUBSTEP
    #undef LDA
    #undef LDB

    // direct epilogue: per (mtl,nt) two 16B stores of 8 consecutive channels
    // global mt = bmt*2 + mtl; Y = 2*(tr*16+h)+mh, X = 2*(tc*8+w)+bmt,
    // ch = 32*mtl + 16*half + r
    #pragma unroll
    for (int nt = 0; nt < 2; nt++) {
        int pxl = nh * 64 + nt * 32 + l31;
        int Y = 2 * (tr * 16 + (pxl >> 3)) + mh;
        int X = 2 * (tc * 8 + (pxl & 7)) + bmt;
        #pragma unroll
        for (int mt = 0; mt < 2; mt++) {
            ushort* up = U + ((size_t)((b * 128 + Y) * 128 + X)) * 64
                       + mt * 32 + half * 16;
            us8 p0, p1;
            #pragma unroll
            for (int i = 0; i < 8; i++) {
                p0[i] = f2bf(acc[mt][nt][i]);
                p1[i] = f2bf(acc[mt][nt][8 + i]);
            }
            *(us8*)up = p0;
            *(us8*)(up + 8) = p1;
        }
    }
}

// ------ re1: conv3x3(U,re_w1)+relu via 16x16x32 MFMA -> R1[b,Y,X,8] ---------
__global__ __launch_bounds__(256, 2) void re1_kernel(const ushort* __restrict__ U,
                                                     const ushort* __restrict__ Aw1,
                                                     ushort* __restrict__ R1) {
    __shared__ ushort Xs[324 * 72];  // 46656 B
    __shared__ ushort As[18 * 64 * 8];
    const int b = blockIdx.y;
    const int ty = blockIdx.x >> 3, tx = blockIdx.x & 7;
    const int tid = threadIdx.x;
    const int wave = tid >> 6, lane = tid & 63;
    const int m16 = lane & 15, kq = lane >> 4;

    for (int idx = tid; idx < 1152; idx += 256)
        *(int4*)&As[idx * 8] = *(const int4*)(Aw1 + (size_t)idx * 8);
    for (int idx = tid; idx < 2592; idx += 256) {
        int px = idx >> 3, q = idx & 7;
        int r = px / 18, c = px - r * 18;
        int gY = ty * 16 - 1 + r, gX = tx * 16 - 1 + c;
        int4 v = {0, 0, 0, 0};
        if ((unsigned)gY < 128u && (unsigned)gX < 128u)
            v = *(const int4*)(U + ((size_t)((b * 128 + gY) * 128 + gX)) * 64 + q * 8);
        *(int4*)&Xs[px * 72 + q * 8] = v;
    }
    __syncthreads();

    f32x4 acc[4];
    #pragma unroll
    for (int nt = 0; nt < 4; nt++)
        #pragma unroll
        for (int r = 0; r < 4; r++) acc[nt][r] = 0.f;

    #pragma unroll 1
    for (int s = 0; s < 18; s++) {
        bf16x8 a = *(const bf16x8*)&As[(s * 64 + lane) * 8];
        int tap = s >> 1, ch = s & 1;
        int ky = tap / 3, kx = tap - ky * 3;
        int xo = (ky * 18 + kx) * 72 + ch * 32 + kq * 8;
        #pragma unroll
        for (int nt = 0; nt < 4; nt++) {
            int row = wave * 4 + nt;
            bf16x8 bv = *(const bf16x8*)&Xs[(row * 18 + m16) * 72 + xo];
            acc[nt] = __builtin_amdgcn_mfma_f32_16x16x32_bf16(a, bv, acc[nt], 0, 0, 0);
        }
    }
    if (kq < 2) {
        #pragma unroll
        for (int nt = 0; nt < 4; nt++) {
            int gY = ty * 16 + wave * 4 + nt, gX = tx * 16 + m16;
            ushort4 pk = {f2bf(fmaxf(acc[nt][0], 0.f)), f2bf(fmaxf(acc[nt][1], 0.f)),
                          f2bf(fmaxf(acc[nt][2], 0.f)), f2bf(fmaxf(acc[nt][3], 0.f))};
            *(ushort4*)(R1 + ((size_t)((b * 128 + gY) * 128 + gX)) * 8 + kq * 4) = pk;
        }
    }
}

// ------ re2: conv3x3(R1,re_w2) + up  via 32x32x16 MFMA -> out f32 planar ----
__global__ __launch_bounds__(256, 2) void re2_kernel(const ushort* __restrict__ R1,
                                                     const ushort* __restrict__ U,
                                                     const ushort* __restrict__ Aw2,
                                                     float* __restrict__ out) {
    __shared__ ushort Xs[324 * 8];   // 5184 B
    __shared__ ushort As[5 * 2 * 64 * 8];
    __shared__ ushort Us[256 * 68];  // 34816 B
    const int b = blockIdx.y;
    const int ty = blockIdx.x >> 3, tx = blockIdx.x & 7;
    const int tid = threadIdx.x;
    const int wave = tid >> 6, lane = tid & 63;
    const int l31 = lane & 31, half = lane >> 5;

    for (int idx = tid; idx < 640; idx += 256)
        *(int4*)&As[idx * 8] = *(const int4*)(Aw2 + (size_t)idx * 8);
    for (int idx = tid; idx < 324; idx += 256) {
        int r = idx / 18, c = idx - r * 18;
        int gY = ty * 16 - 1 + r, gX = tx * 16 - 1 + c;
        int4 v = {0, 0, 0, 0};
        if ((unsigned)gY < 128u && (unsigned)gX < 128u)
            v = *(const int4*)(R1 + ((size_t)((b * 128 + gY) * 128 + gX)) * 8);
        *(int4*)&Xs[idx * 8] = v;
    }
    for (int idx = tid; idx < 2048; idx += 256) {
        int px = idx >> 3, q = idx & 7;
        int gY = ty * 16 + (px >> 4), gX = tx * 16 + (px & 15);
        const ushort* s = U + ((size_t)((b * 128 + gY) * 128 + gX)) * 64 + q * 8;
        ushort4 v0 = *(const ushort4*)s;
        ushort4 v1 = *(const ushort4*)(s + 4);
        *(ushort4*)&Us[px * 68 + q * 8] = v0;
        *(ushort4*)&Us[px * 68 + q * 8 + 4] = v1;
    }
    __syncthreads();

    f32x16 acc[2][2];
    #pragma unroll
    for (int mt = 0; mt < 2; mt++)
        #pragma unroll
        for (int nt = 0; nt < 2; nt++)
            #pragma unroll
            for (int r = 0; r < 16; r++) acc[mt][nt][r] = 0.f;

    #pragma unroll
    for (int s = 0; s < 5; s++) {
        bf16x8 a0 = *(const bf16x8*)&As[((s * 2 + 0) * 64 + lane) * 8];
        bf16x8 a1 = *(const bf16x8*)&As[((s * 2 + 1) * 64 + lane) * 8];
        int t = 2 * s + half;
        if (t > 8) t = 8;  // A is zero there
        int ky = t / 3, kx = t - ky * 3;
        #pragma unroll
        for (int nt = 0; nt < 2; nt++) {
            int pxl = wave * 64 + nt * 32 + l31;
            int row = pxl >> 4, col = pxl & 15;
            bf16x8 bv = *(const bf16x8*)&Xs[((row + ky) * 18 + col + kx) * 8];
            acc[0][nt] = __builtin_amdgcn_mfma_f32_32x32x16_bf16(a0, bv, acc[0][nt], 0, 0, 0);
            acc[1][nt] = __builtin_amdgcn_mfma_f32_32x32x16_bf16(a1, bv, acc[1][nt], 0, 0, 0);
        }
    }
    #pragma unroll
    for (int mt = 0; mt < 2; mt++) {
        #pragma unroll
        for (int nt = 0; nt < 2; nt++) {
            int pxl = wave * 64 + nt * 32 + l31;
            int gY = ty * 16 + (pxl >> 4), gX = tx * 16 + (pxl & 15);
            #pragma unroll
            for (int r = 0; r < 16; r++) {
                int o = mt * 32 + (r & 3) + 8 * (r >> 2) + 4 * half;
                float v = acc[mt][nt][r] + bf2f(Us[pxl * 68 + o]);
                out[((size_t)(b * 64 + o) * 128 + gY) * 128 + gX] = v;
            }
        }
    }
}

extern "C" void kernel_launch(void* const* d_in, const int* in_sizes, int n_in,
                              void* d_out, int out_size, void* d_ws, size_t ws_size,
                              hipStream_t stream) {
    const float* x1      = (const float*)d_in[0];
    const float* x2      = (const float*)d_in[1];
    const float* d1_w1   = (const float*)d_in[2];
    const float* d1_w2   = (const float*)d_in[3];
    const float* d2_w1   = (const float*)d_in[4];
    const float* d2_w2   = (const float*)d_in[5];
    const float* align_w = (const float*)d_in[6];
    const float* up_w1   = (const float*)d_in[7];
    const float* up_w2   = (const float*)d_in[8];
    const float* re_w1   = (const float*)d_in[9];
    const float* re_w2   = (const float*)d_in[10];
    float* out = (float*)d_out;
    float* ws  = (float*)d_ws;

    float*  pooled  = ws + OFF_POOLED;
    float*  pooled2 = ws + OFF_WK;
    ushort* Awt    = (ushort*)(ws + OFF_WT);
    ushort* Wf     = (ushort*)(ws + OFF_WF);
    ushort* Aw1    = (ushort*)(ws + OFF_AW1);
    ushort* Aw2    = (ushort*)(ws + OFF_AW2);
    ushort* bufT   = (ushort*)(ws + OFF_T);
    ushort* R1     = (ushort*)(ws + OFF_T);   // alias (bufT dead by re1)
    ushort* bufAB  = (ushort*)(ws + OFF_AB);
    ushort* bufU   = (ushort*)(ws + OFF_AB);  // alias (bufAB dead after align)
    ushort* F      = (ushort*)(ws + OFF_F);

    head_kernel<<<5305, 256, 0, stream>>>(x1, x2, pooled, up_w1, up_w2, Awt,
                                          align_w, Wf, re_w1, Aw1, re_w2, Aw2);
    dsc1_kernel<<<4096, 256, 0, stream>>>(x1, x2, pooled, d1_w1, d1_w2, bufT, pooled2);
    dsc2_kernel<<<4096, 256, 0, stream>>>(bufT, pooled2, d2_w1, d2_w2, bufAB);

    align_mfma_kernel<<<dim3(32, 16), 256, 0, stream>>>(bufAB, bufAB + 8388608, Wf, F);
    up_mfma_kernel<<<dim3(32, 16), 512, 0, stream>>>(F, Awt, bufU);
    re1_kernel<<<dim3(64, 16), 256, 0, stream>>>(bufU, Aw1, R1);
    re2_kernel<<<dim3(64, 16), 256, 0, stream>>>(R1, bufU, Aw2, out);
}